// Round 1
// baseline (1528.912 us; speedup 1.0000x reference)
//
#include <hip/hip_runtime.h>

#define BB   1024   // batch
#define TT   256    // timesteps
#define FF   23     // lab features
#define HH   100    // hidden
#define G4   400    // 4*H
#define KP   104    // H padded to multiple of 8 (bf16x8 LDS reads)
#define FP   24     // F padded
#define NBW  4      // batch rows per workgroup
#define NTHR 256

typedef unsigned int  u32;
typedef unsigned short u16;

__device__ __forceinline__ float bflo(u32 u){ return __uint_as_float(u << 16); }
__device__ __forceinline__ float bfhi(u32 u){ return __uint_as_float(u & 0xffff0000u); }
// round-to-nearest-even f32 -> bf16 (bit trick; no header type dependence)
__device__ __forceinline__ u16 f2bf(float f){
  u32 u = __float_as_uint(f);
  u += 0x7fffu + ((u >> 16) & 1u);
  return (u16)(u >> 16);
}
__device__ __forceinline__ float fsig(float x){
  return __builtin_amdgcn_rcpf(1.0f + __expf(-x));
}
__device__ __forceinline__ float ftanhx(float x){
  return 1.0f - 2.0f * __builtin_amdgcn_rcpf(__expf(2.0f * x) + 1.0f);
}

__global__ __launch_bounds__(NTHR, 1) void tlstm_fused(
    const float* __restrict__ x_lab,  const float* __restrict__ t_lab,
    const float* __restrict__ x_state,const float* __restrict__ W_x,
    const float* __restrict__ W_h,    const float* __restrict__ b_lstm,
    const float* __restrict__ W_d,    const float* __restrict__ b_d,
    const float* __restrict__ W_state,const float* __restrict__ b_state,
    const float* __restrict__ W_fc,   const float* __restrict__ b_fc,
    float* __restrict__ out)
{
  // bf16 weights, transposed so each thread reads k-contiguous rows.
  __shared__ __align__(16) u16  sWh[G4 * KP];     // [col = g*100+j][k]
  __shared__ __align__(16) u16  sWd[HH * KP];     // [j][k]
  __shared__ __align__(16) u16  sWx[G4 * FP];     // [col][k]
  __shared__ __align__(16) float sH[NBW * KP];    // h state, fp32
  __shared__ __align__(16) float sC[NBW * KP];    // c state, fp32
  __shared__ __align__(16) float sX[2][NBW * FP]; // x(t) double buffer
  __shared__ __align__(16) float sDecay[NBW * TT];// 1/log(e+dt) precomputed

  const int tid = threadIdx.x;
  const int b0  = blockIdx.x * NBW;

  // ---- zero LDS (pads must stay 0; h,c start at 0) ----
  for (int i = tid; i < G4*KP/2; i += NTHR) ((u32*)sWh)[i] = 0u;
  for (int i = tid; i < HH*KP/2; i += NTHR) ((u32*)sWd)[i] = 0u;
  for (int i = tid; i < G4*FP/2; i += NTHR) ((u32*)sWx)[i] = 0u;
  for (int i = tid; i < NBW*KP;  i += NTHR) { sH[i] = 0.f; sC[i] = 0.f; }
  for (int i = tid; i < 2*NBW*FP;i += NTHR) ((float*)sX)[i] = 0.f;
  __syncthreads();

  // ---- stage weights (fp32->bf16), decay table, x(t=0) ----
  for (int i = tid; i < HH*G4; i += NTHR) {
    int k = i / G4, col = i % G4;
    sWh[col*KP + k] = f2bf(W_h[i]);
  }
  for (int i = tid; i < HH*HH; i += NTHR) {
    int k = i / HH, jj = i % HH;
    sWd[jj*KP + k] = f2bf(W_d[i]);
  }
  for (int i = tid; i < FF*G4; i += NTHR) {
    int k = i / G4, col = i % G4;
    sWx[col*FP + k] = f2bf(W_x[i]);
  }
  for (int i = tid; i < NBW*TT; i += NTHR) {
    int bb = i >> 8, t = i & (TT-1);
    sDecay[i] = 1.0f / logf(2.718281828459045f + t_lab[(b0+bb)*TT + t]);
  }
  if (tid < NBW*FP) {
    int sb = tid / FP, sk = tid % FP;
    sX[0][tid] = (sk < FF) ? x_lab[((b0+sb)*TT + 0)*FF + sk] : 0.f;
  }
  __syncthreads();

  // thread = (b2, j): owns cell column j of batch rows b2 and b2+2
  const int b2 = tid & 1;
  const int j  = tid >> 1;
  const bool act = (j < HH);
  const int rA = b2, rB = b2 + 2;

  float bdj = 0.f, bl[4] = {0.f, 0.f, 0.f, 0.f};
  if (act) {
    bdj   = b_d[j];
    bl[0] = b_lstm[j];        bl[1] = b_lstm[HH + j];
    bl[2] = b_lstm[2*HH + j]; bl[3] = b_lstm[3*HH + j];
  }
  float cA = 0.f, cB = 0.f;

  for (int t = 0; t < TT; ++t) {
    // prefetch x(t+1) to registers (hides global latency under compute)
    float xpre = 0.f;
    const int tn = t + 1;
    const int sb = tid / FP, sk = tid % FP;
    if (tid < NBW*FP && tn < TT && sk < FF)
      xpre = x_lab[((b0+sb)*TT + tn)*FF + sk];

    float aA[4], aB[4];
    aA[0]=bl[0]; aA[1]=bl[1]; aA[2]=bl[2]; aA[3]=bl[3];
    aB[0]=bl[0]; aB[1]=bl[1]; aB[2]=bl[2]; aB[3]=bl[3];
    float dA = bdj, dB = bdj;
    float hAn=0.f, cAn=0.f, hBn=0.f, cBn=0.f;

    if (act) {
      // ---- c_short pre-activation: c @ W_d + b_d ----
      for (int kb = 0; kb < KP; kb += 8) {
        float4 cA0 = *(const float4*)&sC[rA*KP + kb];
        float4 cA1 = *(const float4*)&sC[rA*KP + kb + 4];
        float4 cB0 = *(const float4*)&sC[rB*KP + kb];
        float4 cB1 = *(const float4*)&sC[rB*KP + kb + 4];
        uint4 w = *(const uint4*)(sWd + j*KP + kb);
        float w0=bflo(w.x),w1=bfhi(w.x),w2=bflo(w.y),w3=bfhi(w.y);
        float w4=bflo(w.z),w5=bfhi(w.z),w6=bflo(w.w),w7=bfhi(w.w);
        dA += cA0.x*w0 + cA0.y*w1 + cA0.z*w2 + cA0.w*w3
            + cA1.x*w4 + cA1.y*w5 + cA1.z*w6 + cA1.w*w7;
        dB += cB0.x*w0 + cB0.y*w1 + cB0.z*w2 + cB0.w*w3
            + cB1.x*w4 + cB1.y*w5 + cB1.z*w6 + cB1.w*w7;
      }
      // ---- gates: b_lstm + x @ W_x ----
      const float* xrow = sX[t & 1];
      for (int kb = 0; kb < FP; kb += 8) {
        float4 xA0 = *(const float4*)&xrow[rA*FP + kb];
        float4 xA1 = *(const float4*)&xrow[rA*FP + kb + 4];
        float4 xB0 = *(const float4*)&xrow[rB*FP + kb];
        float4 xB1 = *(const float4*)&xrow[rB*FP + kb + 4];
#pragma unroll
        for (int g = 0; g < 4; ++g) {
          uint4 w = *(const uint4*)(sWx + (g*HH + j)*FP + kb);
          float w0=bflo(w.x),w1=bfhi(w.x),w2=bflo(w.y),w3=bfhi(w.y);
          float w4=bflo(w.z),w5=bfhi(w.z),w6=bflo(w.w),w7=bfhi(w.w);
          aA[g] += xA0.x*w0 + xA0.y*w1 + xA0.z*w2 + xA0.w*w3
                 + xA1.x*w4 + xA1.y*w5 + xA1.z*w6 + xA1.w*w7;
          aB[g] += xB0.x*w0 + xB0.y*w1 + xB0.z*w2 + xB0.w*w3
                 + xB1.x*w4 + xB1.y*w5 + xB1.z*w6 + xB1.w*w7;
        }
      }
      // ---- gates: + h @ W_h ----
      for (int kb = 0; kb < KP; kb += 8) {
        float4 hA0 = *(const float4*)&sH[rA*KP + kb];
        float4 hA1 = *(const float4*)&sH[rA*KP + kb + 4];
        float4 hB0 = *(const float4*)&sH[rB*KP + kb];
        float4 hB1 = *(const float4*)&sH[rB*KP + kb + 4];
#pragma unroll
        for (int g = 0; g < 4; ++g) {
          uint4 w = *(const uint4*)(sWh + (g*HH + j)*KP + kb);
          float w0=bflo(w.x),w1=bfhi(w.x),w2=bflo(w.y),w3=bfhi(w.y);
          float w4=bflo(w.z),w5=bfhi(w.z),w6=bflo(w.w),w7=bfhi(w.w);
          aA[g] += hA0.x*w0 + hA0.y*w1 + hA0.z*w2 + hA0.w*w3
                 + hA1.x*w4 + hA1.y*w5 + hA1.z*w6 + hA1.w*w7;
          aB[g] += hB0.x*w0 + hB0.y*w1 + hB0.z*w2 + hB0.w*w3
                 + hB1.x*w4 + hB1.y*w5 + hB1.z*w6 + hB1.w*w7;
        }
      }
      // ---- pointwise T-LSTM update ----
      float decA = sDecay[rA*TT + t], decB = sDecay[rB*TT + t];
      float csA = ftanhx(dA), csB = ftanhx(dB);
      float cadjA = cA - csA + csA*decA;
      float cadjB = cB - csB + csB*decB;
      float iA = fsig(aA[0]), fA = fsig(aA[1]), gA = ftanhx(aA[2]), oA = fsig(aA[3]);
      float iB = fsig(aB[0]), fB = fsig(aB[1]), gB = ftanhx(aB[2]), oB = fsig(aB[3]);
      cAn = fA*cadjA + iA*gA;  hAn = oA*ftanhx(cAn);
      cBn = fB*cadjB + iB*gB;  hBn = oB*ftanhx(cBn);
    }

    __syncthreads();                    // all reads of h/c/x(t) done
    if (act) {
      sH[rA*KP + j] = hAn; sC[rA*KP + j] = cAn; cA = cAn;
      sH[rB*KP + j] = hBn; sC[rB*KP + j] = cBn; cB = cBn;
    }
    if (tid < NBW*FP && tn < TT) sX[tn & 1][tid] = xpre;
    __syncthreads();                    // new state visible
  }

  // ---- epilogue: e_state = x_state@W_state+b_state; y = [h,e]@W_fc+b_fc; softmax ----
  if (tid < NBW) {
    const int bg = b0 + tid;
    float e[20];
#pragma unroll
    for (int k = 0; k < 20; ++k) {
      float a = b_state[k];
#pragma unroll
      for (int s = 0; s < 6; ++s) a += x_state[bg*6 + s] * W_state[s*20 + k];
      e[k] = a;
    }
    float y0 = b_fc[0], y1 = b_fc[1];
    for (int k = 0; k < HH; ++k) {
      float hv = sH[tid*KP + k];
      y0 += hv * W_fc[k*2 + 0];
      y1 += hv * W_fc[k*2 + 1];
    }
#pragma unroll
    for (int k = 0; k < 20; ++k) {
      y0 += e[k] * W_fc[(HH+k)*2 + 0];
      y1 += e[k] * W_fc[(HH+k)*2 + 1];
    }
    float m = fmaxf(y0, y1);
    float e0 = __expf(y0 - m), e1 = __expf(y1 - m);
    float inv = 1.0f / (e0 + e1);
    out[bg*2 + 0] = e0 * inv;
    out[bg*2 + 1] = e1 * inv;
  }
}

extern "C" void kernel_launch(void* const* d_in, const int* in_sizes, int n_in,
                              void* d_out, int out_size, void* d_ws, size_t ws_size,
                              hipStream_t stream) {
  const float* x_lab   = (const float*)d_in[0];
  const float* t_lab   = (const float*)d_in[1];
  const float* x_state = (const float*)d_in[2];
  const float* W_x     = (const float*)d_in[3];
  const float* W_h     = (const float*)d_in[4];
  const float* b_lstm  = (const float*)d_in[5];
  const float* W_d     = (const float*)d_in[6];
  const float* b_d     = (const float*)d_in[7];
  const float* W_state = (const float*)d_in[8];
  const float* b_state = (const float*)d_in[9];
  const float* W_fc    = (const float*)d_in[10];
  const float* b_fc    = (const float*)d_in[11];
  float* outp = (float*)d_out;

  hipLaunchKernelGGL(tlstm_fused, dim3(BB / NBW), dim3(NTHR), 0, stream,
                     x_lab, t_lab, x_state, W_x, W_h, b_lstm, W_d, b_d,
                     W_state, b_state, W_fc, b_fc, outp);
}

// Round 2
// 394.071 us; speedup vs baseline: 3.8798x; 3.8798x over previous
//
#include <hip/hip_runtime.h>

#define TT   256    // timesteps
#define FF   23     // lab features
#define HH   100    // hidden
#define NROW 16     // batch rows per workgroup (one M=16 MFMA tile)
#define NTHR 512    // 8 waves
#define NWG  64     // 1024 / NROW

typedef unsigned int  u32;
typedef unsigned short u16;
typedef __attribute__((ext_vector_type(8))) short short8;  // 8 bf16 in 4 VGPRs
typedef __attribute__((ext_vector_type(4))) float f32x4;

__device__ __forceinline__ u16 f2bf(float f){           // RTNE f32->bf16
  u32 u = __float_as_uint(f);
  u += 0x7fffu + ((u >> 16) & 1u);
  return (u16)(u >> 16);
}
__device__ __forceinline__ float fsig(float x){
  return __builtin_amdgcn_rcpf(1.0f + __expf(-x));
}
__device__ __forceinline__ float ftanh(float x){
  return 1.0f - 2.0f * __builtin_amdgcn_rcpf(__expf(2.0f * x) + 1.0f);
}

// A-frag staging layout (bf16, 16 rows x 128 k): short_idx(row,k) =
//   (k>>5)*512 + ((k>>3)&3)*128 + row*8 + (k&7)
// => lane reads its 16x16x32 A-frag as 8 contiguous shorts at kf*512 + lane*8
//    (row = lane&15, k = kf*32 + (lane>>4)*8 + i)  -- conflict-free ds_read_b128.

__global__ __launch_bounds__(NTHR, 2) void tlstm_mfma(
    const float* __restrict__ x_lab,  const float* __restrict__ t_lab,
    const float* __restrict__ x_state,const float* __restrict__ W_x,
    const float* __restrict__ W_h,    const float* __restrict__ b_lstm,
    const float* __restrict__ W_d,    const float* __restrict__ b_d,
    const float* __restrict__ W_state,const float* __restrict__ b_state,
    const float* __restrict__ W_fc,   const float* __restrict__ b_fc,
    float* __restrict__ out)
{
  __shared__ short sHC[2][2][2048];            // [buf][h=0/c=1][16 rows x 128 k bf16, frag-swizzled]
  __shared__ short sX[2][512];                 // [buf][16 rows x 32 k bf16, frag-swizzled]
  __shared__ __align__(16) float sDec[TT][16]; // decay per (t, row)
  __shared__ __align__(16) float sHF[16][128]; // fp32 h_final for epilogue

  const int tid  = threadIdx.x;
  const int lane = tid & 63;
  const int w    = tid >> 6;        // wave 0..7
  const int nl   = lane & 15;       // n within tile / A row
  const int q4   = lane >> 4;       // quarter-wave
  const int b0   = blockIdx.x * NROW;
  const int j    = 8 * nl + w;      // hidden column owned by this lane (0..127; real < 100)
  const bool jr  = (j < HH);

  // ---- zero h/c staging (t=0 state = 0; pads stay 0) ----
  for (int i = tid; i < 2*2*2048; i += NTHR) ((short*)sHC)[i] = 0;
  for (int i = tid; i < 2*512;    i += NTHR) ((short*)sX)[i]  = 0;

  // ---- persistent weight fragments in VGPRs (B-operand layout:
  //      col = lane&15 -> j = 8*nl + w ; k = kf*32 + q4*8 + i) ----
  short8 wh[4][4], wd[4], wx[4];
#pragma unroll
  for (int g = 0; g < 4; ++g)
#pragma unroll
    for (int kf = 0; kf < 4; ++kf) {
      short8 v;
#pragma unroll
      for (int i = 0; i < 8; ++i) {
        int k = kf*32 + q4*8 + i;
        float x = (k < HH && jr) ? W_h[k*400 + g*HH + j] : 0.f;
        v[i] = (short)f2bf(x);
      }
      wh[g][kf] = v;
    }
#pragma unroll
  for (int kf = 0; kf < 4; ++kf) {
    short8 v;
#pragma unroll
    for (int i = 0; i < 8; ++i) {
      int k = kf*32 + q4*8 + i;
      float x = (k < HH && jr) ? W_d[k*HH + j] : 0.f;
      v[i] = (short)f2bf(x);
    }
    wd[kf] = v;
  }
#pragma unroll
  for (int g = 0; g < 4; ++g) {
    short8 v;
#pragma unroll
    for (int i = 0; i < 8; ++i) {
      int k = q4*8 + i;                       // single K-frag (F=23 pad 32)
      float x = (k < FF && jr) ? W_x[k*400 + g*HH + j] : 0.f;
      v[i] = (short)f2bf(x);
    }
    wx[g] = v;
  }

  // ---- biases per lane ----
  float bl[4], bd;
#pragma unroll
  for (int g = 0; g < 4; ++g) bl[g] = jr ? b_lstm[g*HH + j] : 0.f;
  bd = jr ? b_d[j] : 0.f;

  // ---- decay table + x(t=0) staging ----
  for (int e = tid; e < TT*16; e += NTHR) {
    int t = e >> 4, r = e & 15;
    sDec[t][r] = 1.0f / logf(2.718281828459045f + t_lab[(b0 + r)*TT + t]);
  }
  for (int e = tid; e < NROW*FF; e += NTHR) {
    int r = e / FF, f = e % FF;
    sX[0][(f >> 3)*128 + r*8 + (f & 7)] = (short)f2bf(x_lab[((b0 + r)*TT + 0)*FF + f]);
  }

  // x-prefetch assignment (constant per thread)
  const bool px = (tid < NROW*FF);
  const int  pr = tid / FF, pf = tid % FF;
  const int  xoff = ((b0 + pr)*TT)*FF + pf;       // + (t+1)*FF per step
  // h/c write base (this lane's column j, swizzled)
  const int wbase = (j >> 5)*512 + ((j >> 3) & 3)*128 + (j & 7);

  float cm[4] = {0.f, 0.f, 0.f, 0.f};   // fp32 master cell state (rows q4*4+r)
  float hl[4] = {0.f, 0.f, 0.f, 0.f};   // last h (fp32) for epilogue

  __syncthreads();

  for (int t = 0; t < TT; ++t) {
    const short* hb = sHC[t & 1][0];
    const short* cb = sHC[t & 1][1];

    // A-fragments: h, c, x  (row = nl, k = kf*32 + q4*8 + i)
    short8 ha[4], ca[4];
#pragma unroll
    for (int kf = 0; kf < 4; ++kf) {
      ha[kf] = *(const short8*)(hb + kf*512 + lane*8);
      ca[kf] = *(const short8*)(cb + kf*512 + lane*8);
    }
    short8 xa = *(const short8*)(sX[t & 1] + lane*8);
    f32x4 dec = *(const f32x4*)&sDec[t][q4*4];

    // prefetch x(t+1) from global (latency hidden under MFMA)
    float xp = 0.f;
    if (px && t + 1 < TT) xp = x_lab[xoff + (t + 1)*FF];

    // ---- c_short pre-activation: c @ W_d + b_d ----
    f32x4 accD = {bd, bd, bd, bd};
#pragma unroll
    for (int kf = 0; kf < 4; ++kf)
      accD = __builtin_amdgcn_mfma_f32_16x16x32_bf16(ca[kf], wd[kf], accD, 0, 0, 0);

    // ---- gates: b + x@W_x + h@W_h ----
    f32x4 acc[4];
#pragma unroll
    for (int g = 0; g < 4; ++g) {
      f32x4 a = {bl[g], bl[g], bl[g], bl[g]};
      a = __builtin_amdgcn_mfma_f32_16x16x32_bf16(xa, wx[g], a, 0, 0, 0);
#pragma unroll
      for (int kf = 0; kf < 4; ++kf)
        a = __builtin_amdgcn_mfma_f32_16x16x32_bf16(ha[kf], wh[g][kf], a, 0, 0, 0);
      acc[g] = a;
    }

    // ---- pointwise T-LSTM update (lane-local in C/D layout) ----
    short* hn = sHC[(t + 1) & 1][0];
    short* cn = sHC[(t + 1) & 1][1];
#pragma unroll
    for (int r = 0; r < 4; ++r) {
      float cs   = ftanh(accD[r]);
      float cadj = cm[r] - cs + cs*dec[r];
      float ig = fsig(acc[0][r]);
      float fg = fsig(acc[1][r]);
      float gg = ftanh(acc[2][r]);
      float og = fsig(acc[3][r]);
      float cnv = fg*cadj + ig*gg;
      cm[r] = cnv;
      float hv = og*ftanh(cnv);
      hl[r] = hv;
      int idx = wbase + (q4*4 + r)*8;
      hn[idx] = (short)f2bf(hv);
      cn[idx] = (short)f2bf(cnv);
    }
    if (px && t + 1 < TT)
      sX[(t + 1) & 1][(pf >> 3)*128 + pr*8 + (pf & 7)] = (short)f2bf(xp);

    __syncthreads();
  }

  // ---- epilogue: fp32 h_final -> LDS, then tiny FC + softmax ----
#pragma unroll
  for (int r = 0; r < 4; ++r) sHF[q4*4 + r][j] = hl[r];
  __syncthreads();

  if (tid < NROW) {
    const int bg = b0 + tid;
    float y0 = b_fc[0], y1 = b_fc[1];
    for (int k = 0; k < HH; ++k) {
      float hv = sHF[tid][k];
      y0 += hv * W_fc[2*k];
      y1 += hv * W_fc[2*k + 1];
    }
#pragma unroll
    for (int k = 0; k < 20; ++k) {
      float a = b_state[k];
#pragma unroll
      for (int s = 0; s < 6; ++s) a += x_state[bg*6 + s] * W_state[s*20 + k];
      y0 += a * W_fc[2*(HH + k)];
      y1 += a * W_fc[2*(HH + k) + 1];
    }
    float m = fmaxf(y0, y1);
    float e0 = __expf(y0 - m), e1 = __expf(y1 - m);
    float inv = 1.0f / (e0 + e1);
    out[bg*2 + 0] = e0 * inv;
    out[bg*2 + 1] = e1 * inv;
  }
}

extern "C" void kernel_launch(void* const* d_in, const int* in_sizes, int n_in,
                              void* d_out, int out_size, void* d_ws, size_t ws_size,
                              hipStream_t stream) {
  const float* x_lab   = (const float*)d_in[0];
  const float* t_lab   = (const float*)d_in[1];
  const float* x_state = (const float*)d_in[2];
  const float* W_x     = (const float*)d_in[3];
  const float* W_h     = (const float*)d_in[4];
  const float* b_lstm  = (const float*)d_in[5];
  const float* W_d     = (const float*)d_in[6];
  const float* b_d     = (const float*)d_in[7];
  const float* W_state = (const float*)d_in[8];
  const float* b_state = (const float*)d_in[9];
  const float* W_fc    = (const float*)d_in[10];
  const float* b_fc    = (const float*)d_in[11];
  float* outp = (float*)d_out;

  hipLaunchKernelGGL(tlstm_mfma, dim3(NWG), dim3(NTHR), 0, stream,
                     x_lab, t_lab, x_state, W_x, W_h, b_lstm, W_d, b_d,
                     W_state, b_state, W_fc, b_fc, outp);
}

// Round 3
// 186.509 us; speedup vs baseline: 8.1975x; 2.1129x over previous
//
#include <hip/hip_runtime.h>

#define TT   256    // timesteps
#define FF   23     // lab features
#define HH   100    // hidden
#define NROW 4      // batch rows per workgroup
#define NTHR 512    // 8 waves
#define NWG  256    // 1024 / NROW -> one wg per CU

typedef unsigned int  u32;
typedef unsigned short u16;
typedef __attribute__((ext_vector_type(8))) short short8;  // 8 bf16 in 4 VGPRs
typedef __attribute__((ext_vector_type(4))) float f32x4;

__device__ __forceinline__ u16 f2bf(float f){           // RTNE f32->bf16
  u32 u = __float_as_uint(f);
  u += 0x7fffu + ((u >> 16) & 1u);
  return (u16)(u >> 16);
}
__device__ __forceinline__ float fsig(float x){
  return __builtin_amdgcn_rcpf(1.0f + __expf(-x));
}
__device__ __forceinline__ float ftanh(float x){
  return 1.0f - 2.0f * __builtin_amdgcn_rcpf(__expf(2.0f * x) + 1.0f);
}

// LDS layouts (bf16):
//  h/c: idx(b, k) = (k>>5)*128 + b*32 + ((k>>3)&3)*8 + (k&7)   [kf][b][q4][i]
//       lane (q4, nl) with nl&3==0 reads its A-frag (tile-row nl = 4b) as
//       8 contiguous shorts at kf*128 + (nl>>2)*32 + q4*8  -> 2-way banks (free).
//  x:   idx(b, k) = b*32 + k   (K=32 frag; k=24..27 carry h[96..99] fold)
// Batch row b sits at MFMA tile-row 4b, so C/D reg r=0 of every lane is real.

__global__ __launch_bounds__(NTHR, 2) void tlstm4(
    const float* __restrict__ x_lab,  const float* __restrict__ t_lab,
    const float* __restrict__ x_state,const float* __restrict__ W_x,
    const float* __restrict__ W_h,    const float* __restrict__ b_lstm,
    const float* __restrict__ W_d,    const float* __restrict__ b_d,
    const float* __restrict__ W_state,const float* __restrict__ b_state,
    const float* __restrict__ W_fc,   const float* __restrict__ b_fc,
    float* __restrict__ out)
{
  __shared__ __align__(16) short sHC[2][2][512];  // [buf][h=0/c=1][..]
  __shared__ __align__(16) short sX[2][128];      // [buf][b*32+k]
  __shared__ __align__(16) float sDec[TT * NROW]; // [t*4 + b]
  __shared__ __align__(16) float sHF[NROW][128];  // fp32 h_final

  const int tid  = threadIdx.x;
  const int lane = tid & 63;
  const int w    = tid >> 6;        // wave 0..7
  const int nl   = lane & 15;
  const int q4   = lane >> 4;
  const int b0   = blockIdx.x * NROW;
  const int j    = w * 16 + nl;     // hidden column (waves 0..6 real, <=111)
  const bool jr  = (j < HH);

  // ---- zero LDS state buffers (pads must stay 0) ----
  for (int i = tid; i < 2*2*512; i += NTHR) ((short*)sHC)[i] = 0;
  for (int i = tid; i < 2*128;   i += NTHR) ((short*)sX)[i]  = 0;

  // ---- decay table + x(t=0) ----
  for (int e = tid; e < TT*NROW; e += NTHR) {
    int t = e >> 2, r = e & 3;
    sDec[e] = 1.0f / logf(2.718281828459045f + t_lab[(b0 + r)*TT + t]);
  }
  if (tid < NROW*FF) {
    int r = tid / FF, f = tid % FF;
    sX[0][r*32 + f] = (short)f2bf(x_lab[((b0 + r)*TT + 0)*FF + f]);
  }

  // ---- persistent weight fragments (B-operand: col=nl -> j, k=kf*32+q4*8+i) ----
  short8 wh[4][3], wd[4], wx[4];
#pragma unroll
  for (int g = 0; g < 4; ++g)
#pragma unroll
    for (int kf = 0; kf < 3; ++kf) {
      short8 v;
#pragma unroll
      for (int i = 0; i < 8; ++i) {
        int k = kf*32 + q4*8 + i;                 // k <= 95: always real row
        v[i] = (short)(jr ? f2bf(W_h[k*400 + g*HH + j]) : 0);
      }
      wh[g][kf] = v;
    }
#pragma unroll
  for (int kf = 0; kf < 4; ++kf) {
    short8 v;
#pragma unroll
    for (int i = 0; i < 8; ++i) {
      int k = kf*32 + q4*8 + i;
      v[i] = (short)((k < HH && jr) ? f2bf(W_d[k*HH + j]) : 0);
    }
    wd[kf] = v;
  }
#pragma unroll
  for (int g = 0; g < 4; ++g) {
    short8 v;
#pragma unroll
    for (int i = 0; i < 8; ++i) {
      int k = q4*8 + i;
      float x = 0.f;
      if (jr) {
        if (k < FF)                 x = W_x[k*400 + g*HH + j];
        else if (k >= 24 && k < 28) x = W_h[(96 + (k-24))*400 + g*HH + j]; // h-fold
      }
      v[i] = (short)f2bf(x);
    }
    wx[g] = v;
  }

  float bl[4], bd;
#pragma unroll
  for (int g = 0; g < 4; ++g) bl[g] = jr ? b_lstm[g*HH + j] : 0.f;
  bd = jr ? b_d[j] : 0.f;

  __syncthreads();

  // A-frag read predicate: tile-row nl must be 4b
  const bool rdr  = ((nl & 3) == 0);
  const int rbase = (nl >> 2)*32 + q4*8;
  // h/c writeback slot for (b=q4, k=j)
  const int widx  = (j >> 5)*128 + q4*32 + ((j >> 3) & 3)*8 + (j & 7);

  short8 ha[3] = {}, ca[4] = {}, xa = {};   // stay 0 in masked lanes
  float cm = 0.f;                            // fp32 master cell (b=q4, j)
  float hl = 0.f;

  for (int t = 0; t < TT; ++t) {
    if (w < 7) {
      const short* hb = sHC[t & 1][0];
      const short* cb = sHC[t & 1][1];
      if (rdr) {
#pragma unroll
        for (int kf = 0; kf < 3; ++kf) ha[kf] = *(const short8*)(hb + kf*128 + rbase);
#pragma unroll
        for (int kf = 0; kf < 4; ++kf) ca[kf] = *(const short8*)(cb + kf*128 + rbase);
        xa = *(const short8*)(sX[t & 1] + rbase);
      }
      float dec = sDec[t*4 + q4];

      f32x4 accD = {bd, bd, bd, bd};
#pragma unroll
      for (int kf = 0; kf < 4; ++kf)
        accD = __builtin_amdgcn_mfma_f32_16x16x32_bf16(ca[kf], wd[kf], accD, 0, 0, 0);

      f32x4 acc[4];
#pragma unroll
      for (int g = 0; g < 4; ++g) {
        f32x4 a = {bl[g], bl[g], bl[g], bl[g]};
        a = __builtin_amdgcn_mfma_f32_16x16x32_bf16(xa, wx[g], a, 0, 0, 0); // x + h[96..99]
#pragma unroll
        for (int kf = 0; kf < 3; ++kf)
          a = __builtin_amdgcn_mfma_f32_16x16x32_bf16(ha[kf], wh[g][kf], a, 0, 0, 0);
        acc[g] = a;
      }

      // ---- pointwise (reg r=0 is batch row b=q4) ----
      float cs   = ftanh(accD[0]);
      float cadj = cm - cs + cs*dec;
      float ig = fsig(acc[0][0]);
      float fg = fsig(acc[1][0]);
      float gg = ftanh(acc[2][0]);
      float og = fsig(acc[3][0]);
      float cnv = fg*cadj + ig*gg;
      cm = cnv;
      float hv = og*ftanh(cnv);
      hl = hv;

      short* hn = sHC[(t + 1) & 1][0];
      short* cn = sHC[(t + 1) & 1][1];
      hn[widx] = (short)f2bf(hv);
      cn[widx] = (short)f2bf(cnv);
      if (w == 6 && nl < 4)                        // h[96..99] -> x-frag k=24..27
        sX[(t + 1) & 1][q4*32 + 24 + nl] = (short)f2bf(hv);
    } else {
      // wave 7: prefetch x(t+1) into the other x buffer
      if (t + 1 < TT) {
        int e0 = lane;
        if (e0 < NROW*FF) {
          int pr = e0 / FF, pf = e0 % FF;
          sX[(t + 1) & 1][pr*32 + pf] =
              (short)f2bf(x_lab[((b0 + pr)*TT + (t + 1))*FF + pf]);
        }
        int e1 = lane + 64;
        if (e1 < NROW*FF) {
          int pr = e1 / FF, pf = e1 % FF;
          sX[(t + 1) & 1][pr*32 + pf] =
              (short)f2bf(x_lab[((b0 + pr)*TT + (t + 1))*FF + pf]);
        }
      }
    }
    __syncthreads();
  }

  // ---- epilogue ----
  if (w < 7) sHF[q4][j] = hl;
  __syncthreads();

  if (tid < NROW) {
    const int bg = b0 + tid;
    float y0 = b_fc[0], y1 = b_fc[1];
    for (int k = 0; k < HH; ++k) {
      float hv = sHF[tid][k];
      y0 += hv * W_fc[2*k];
      y1 += hv * W_fc[2*k + 1];
    }
#pragma unroll
    for (int k = 0; k < 20; ++k) {
      float a = b_state[k];
#pragma unroll
      for (int s = 0; s < 6; ++s) a += x_state[bg*6 + s] * W_state[s*20 + k];
      y0 += a * W_fc[2*(HH + k)];
      y1 += a * W_fc[2*(HH + k) + 1];
    }
    float m = fmaxf(y0, y1);
    float e0 = __expf(y0 - m), e1 = __expf(y1 - m);
    float inv = 1.0f / (e0 + e1);
    out[bg*2 + 0] = e0 * inv;
    out[bg*2 + 1] = e1 * inv;
  }
}

extern "C" void kernel_launch(void* const* d_in, const int* in_sizes, int n_in,
                              void* d_out, int out_size, void* d_ws, size_t ws_size,
                              hipStream_t stream) {
  const float* x_lab   = (const float*)d_in[0];
  const float* t_lab   = (const float*)d_in[1];
  const float* x_state = (const float*)d_in[2];
  const float* W_x     = (const float*)d_in[3];
  const float* W_h     = (const float*)d_in[4];
  const float* b_lstm  = (const float*)d_in[5];
  const float* W_d     = (const float*)d_in[6];
  const float* b_d     = (const float*)d_in[7];
  const float* W_state = (const float*)d_in[8];
  const float* b_state = (const float*)d_in[9];
  const float* W_fc    = (const float*)d_in[10];
  const float* b_fc    = (const float*)d_in[11];
  float* outp = (float*)d_out;

  hipLaunchKernelGGL(tlstm4, dim3(NWG), dim3(NTHR), 0, stream,
                     x_lab, t_lab, x_state, W_x, W_h, b_lstm, W_d, b_d,
                     W_state, b_state, W_fc, b_fc, outp);
}